// Round 6
// baseline (149.890 us; speedup 1.0000x reference)
//
#include <hip/hip_runtime.h>

// Problem constants (fixed by reference setup_inputs)
#define BATCH 8
#define NPTS  4096   // N == M == 4096
#define KD    64
#define MQ    8      // m-strips: each block walks 512 cols = 4 tiles of 128
#define WALK  4
#define FINF  3.0e38f

typedef float f32x4 __attribute__((ext_vector_type(4)));
typedef float f32x2 __attribute__((ext_vector_type(2)));
typedef short s16x8 __attribute__((ext_vector_type(8)));

__device__ __forceinline__ unsigned int f2bf(float f) {
  // round-to-nearest-even fp32 -> bf16 (inputs finite)
  unsigned int u = __float_as_uint(f);
  u += 0x7FFFu + ((u >> 16) & 1u);
  return u >> 16;
}

// ---------------------------------------------------------------------------
// Prepass: convert X,Y (fp32 [32768][64]) to bf16 packed (uint [32768][32])
// and compute exact fp32 squared norms. 32 threads per row, 2 floats/thread.
// Also zeroes the reduce-phase counter (stream order makes this race-free).
__global__ __launch_bounds__(256)
void prep_kernel(const float* __restrict__ X, const float* __restrict__ Y,
                 unsigned int* __restrict__ Xbf, unsigned int* __restrict__ Ybf,
                 float* __restrict__ x2, float* __restrict__ y2,
                 unsigned int* __restrict__ counter) {
  int gid = blockIdx.x * 256 + threadIdx.x;
  if (gid == 0) *counter = 0;
  int row = gid >> 5;
  int ki  = gid & 31;
  bool isX = row < BATCH * NPTS;
  int r2 = row & (BATCH * NPTS - 1);
  const float* src = isX ? X : Y;
  f32x2 v = *(const f32x2*)(src + (size_t)r2 * KD + ki * 2);
  float s = v[0] * v[0] + v[1] * v[1];
  #pragma unroll
  for (int m = 16; m >= 1; m >>= 1) s += __shfl_xor(s, m, 64);  // stays in 32-lane half
  unsigned int packed = (f2bf(v[1]) << 16) | f2bf(v[0]);
  (isX ? Xbf : Ybf)[r2 * 32 + ki] = packed;
  if (ki == 0) (isX ? x2 : y2)[r2] = s;
}

// ---------------------------------------------------------------------------
// Main: block = (mq, ntile, b). 128 rows x 512 cols (4 m-tiles of 128).
// Waves in 2x2; wave tile 64x64 per m-tile. BARRIER-FREE K-walk: no LDS
// staging at all — A/B MFMA fragments are loaded directly from global (L2-hot;
// FETCH_SIZE ~41 MB in r4 proved L2/L3 serve the re-reads). Fragment address
// for 16x16x32 bf16 is just row*128B + ks*64B + q*16B (16B-aligned dwordx4).
// This kills the per-tt __syncthreads + vmcnt(0) drain that throttled the
// LDS-staged versions (m97-structure stall). First barrier is the epilogue.
__global__ __launch_bounds__(256, 2)
void chamfer_main(const unsigned short* __restrict__ Xbf,
                  const unsigned short* __restrict__ Ybf,
                  const float* __restrict__ x2g, const float* __restrict__ y2g,
                  float* __restrict__ rowpart,   // [MQ][B*N] min over strip cols (sq)
                  float* __restrict__ colpart) { // [32][B*M] min over ntile rows (sq)
  __shared__ float l_redf[4 * 64];     // 1 KB: per-wave row-mins
  __shared__ float l_cred[2 * 512];    // 4 KB: [rowgroup][strip col] col-mins

  const int mq = blockIdx.x, ntile = blockIdx.y, b = blockIdx.z;
  const int n0 = ntile * 128;
  const int mbase = mq * 512;
  const int t = threadIdx.x, w = t >> 6, lane = t & 63, c = lane & 15, q = lane >> 4;
  const int wr = (w >> 1) * 64, wc = (w & 1) * 64, rg = w >> 1;

  const unsigned short* Xg = Xbf + (size_t)(b * NPTS + n0) * KD;
  const unsigned short* Yg = Ybf + (size_t)(b * NPTS + mbase) * KD;

  // X fragments direct global->reg (A layout: m=c, k=q*8..q*8+7 per ks-half).
  s16x8 xf[4][2];
  #pragma unroll
  for (int i = 0; i < 4; ++i) {
    const unsigned short* xr = Xg + (wr + i * 16 + c) * KD + q * 8;
    xf[i][0] = *(const s16x8*)xr;
    xf[i][1] = *(const s16x8*)(xr + 32);
  }

  // x2 fragment (rows wr + i*16 + q*4 + r), fp32, L2-hot. 16 VGPRs.
  const float* x2b = x2g + b * NPTS + n0;
  f32x4 x2r[4];
  #pragma unroll
  for (int i = 0; i < 4; ++i) x2r[i] = *(const f32x4*)(x2b + wr + i * 16 + q * 4);

  float rm[4][4];
  #pragma unroll
  for (int i = 0; i < 4; ++i)
    #pragma unroll
    for (int r = 0; r < 4; ++r) rm[i][r] = FINF;

  const float* y2b = y2g + b * NPTS + mbase;
  const f32x4 zacc = {0.f, 0.f, 0.f, 0.f};

  #pragma unroll
  for (int tt = 0; tt < WALK; ++tt) {
    // All of this tt's B fragments + y2: 8 dwordx4 + 4 dword, issued together
    // (independent L2 loads — latency hidden by ILP + 3 waves/SIMD).
    s16x8 yf[4][2];
    float y2c[4];
    #pragma unroll
    for (int j = 0; j < 4; ++j) {
      const unsigned short* yr = Yg + (tt * 128 + wc + j * 16 + c) * KD + q * 8;
      yf[j][0] = *(const s16x8*)yr;
      yf[j][1] = *(const s16x8*)(yr + 32);
      y2c[j] = y2b[tt * 128 + wc + j * 16 + c];
    }

    float cmj[4];
    #pragma unroll
    for (int j = 0; j < 4; ++j) {
      f32x4 acc[4];
      #pragma unroll
      for (int i = 0; i < 4; ++i) {
        f32x4 a0 = __builtin_amdgcn_mfma_f32_16x16x32_bf16(xf[i][0], yf[j][0], zacc, 0, 0, 0);
        acc[i] = __builtin_amdgcn_mfma_f32_16x16x32_bf16(xf[i][1], yf[j][1], a0, 0, 0, 0);
      }
      float cm = FINF;
      #pragma unroll
      for (int i = 0; i < 4; ++i)
        #pragma unroll
        for (int r = 0; r < 4; ++r) {
          float v = acc[i][r];
          rm[i][r] = fminf(rm[i][r], fmaf(-2.f, v, y2c[j]));
          cm = fminf(cm, fmaf(-2.f, v, x2r[i][r]));
        }
      // col-min over this wave's 64 rows: reduce across the 4 q-groups
      cm = fminf(cm, __shfl_xor(cm, 16, 64));
      cm = fminf(cm, __shfl_xor(cm, 32, 64));
      cmj[j] = cm;
    }
    // quad q stores col group j==q: one ds_write, 64 consecutive floats/wave.
    // Slots are wave-private across all tt -> no barrier needed until the end.
    float cmq = (q == 0) ? cmj[0] : (q == 1) ? cmj[1] : (q == 2) ? cmj[2] : cmj[3];
    l_cred[rg * 512 + tt * 128 + wc + q * 16 + c] = cmq;
  }

  // Row-min: reduce over the 16 c-lanes within each q-group...
  #pragma unroll
  for (int msk = 1; msk <= 8; msk <<= 1)
    #pragma unroll
    for (int i = 0; i < 4; ++i)
      #pragma unroll
      for (int r = 0; r < 4; ++r)
        rm[i][r] = fminf(rm[i][r], __shfl_xor(rm[i][r], msk, 64));
  // ...then store per-wave row-mins to LDS (literal indices only).
  if (c == 0) {
    #pragma unroll
    for (int i = 0; i < 4; ++i) {
      f32x4 v = {rm[i][0], rm[i][1], rm[i][2], rm[i][3]};
      *(f32x4*)&l_redf[w * 64 + i * 16 + q * 4] = v;
    }
  }
  __syncthreads();  // the ONLY barrier in the kernel

  if (t < 128) {
    // combine the 2 col-group waves of each row group, add x2, store
    int g = t >> 6, lr = t & 63;
    float v = fminf(l_redf[(g * 2) * 64 + lr], l_redf[(g * 2 + 1) * 64 + lr]);
    rowpart[mq * (BATCH * NPTS) + b * NPTS + n0 + t] = v + x2b[t];
  } else {
    // combine the 2 row groups for each of the 512 strip cols, add y2, store
    float* colrow = colpart + (size_t)(ntile * 8 + b) * NPTS + mbase;
    int ct = t - 128;
    #pragma unroll
    for (int u = 0; u < 4; ++u) {
      int cc = ct + u * 128;
      float v = fminf(l_cred[cc], l_cred[512 + cc]);
      colrow[cc] = v + y2b[cc];
    }
  }
}

// ---------------------------------------------------------------------------
// Final: min over partials, sqrt, mean — self-finalizing (no memset op). The
// last block (device-scope ticket) sums the 128 block partials -> scalar out.
__global__ __launch_bounds__(256)
void reduce_kernel(const float* __restrict__ rowpart, const float* __restrict__ colpart,
                   float* __restrict__ partials, unsigned int* __restrict__ counter,
                   float* __restrict__ out) {
  int i = blockIdx.x * 256 + threadIdx.x;
  const int TOT = BATCH * NPTS;
  float rv = FINF;
  #pragma unroll
  for (int s = 0; s < MQ; ++s) rv = fminf(rv, rowpart[s * TOT + i]);
  float s0 = sqrtf(fmaxf(rv, 0.f));
  float cv = FINF;
  #pragma unroll
  for (int nt = 0; nt < 32; ++nt) cv = fminf(cv, colpart[nt * TOT + i]);
  s0 += sqrtf(fmaxf(cv, 0.f));
  #pragma unroll
  for (int m = 32; m >= 1; m >>= 1) s0 += __shfl_xor(s0, m, 64);
  __shared__ float wsum[4];
  if ((threadIdx.x & 63) == 0) wsum[threadIdx.x >> 6] = s0;
  __syncthreads();

  if (threadIdx.x < 64) {  // wave 0 publishes the block partial, then maybe finalizes
    unsigned int ticket = 0;
    if (threadIdx.x == 0) {
      float bsum = wsum[0] + wsum[1] + wsum[2] + wsum[3];
      atomicExch(&partials[blockIdx.x], bsum);  // device-scope visible store
      __threadfence();
      ticket = atomicAdd(counter, 1);
    }
    ticket = __shfl(ticket, 0, 64);
    if (ticket == 127) {  // all 128 partials published
      float v = atomicAdd(&partials[threadIdx.x], 0.0f) +
                atomicAdd(&partials[threadIdx.x + 64], 0.0f);
      #pragma unroll
      for (int m = 32; m >= 1; m >>= 1) v += __shfl_xor(v, m, 64);
      if (threadIdx.x == 0) out[0] = v * (1.0f / (float)TOT);
    }
  }
}

// ---------------------------------------------------------------------------
extern "C" void kernel_launch(void* const* d_in, const int* in_sizes, int n_in,
                              void* d_out, int out_size, void* d_ws, size_t ws_size,
                              hipStream_t stream) {
  const float* X = (const float*)d_in[0];  // [B, N, 64] fp32
  const float* Y = (const float*)d_in[1];  // [B, M, 64] fp32
  float* out = (float*)d_out;

  // Workspace layout (bytes):
  //   Xbf 4MB | Ybf 4MB | x2 128KB | y2 128KB | rowpart 1MB | colpart 4MB
  //   | partials 512B | counter 4B
  char* ws = (char*)d_ws;
  unsigned int* Xbf = (unsigned int*)ws;                       // packed bf16 pairs
  unsigned int* Ybf = (unsigned int*)(ws + (4u << 20));
  float* x2 = (float*)(ws + (8u << 20));
  float* y2 = (float*)(ws + (8u << 20) + (128u << 10));
  float* rowpart = (float*)(ws + (8u << 20) + (256u << 10));
  float* colpart = (float*)(ws + (9u << 20) + (256u << 10));
  float* partials = (float*)(ws + (13u << 20) + (256u << 10));
  unsigned int* counter = (unsigned int*)(partials + 128);

  // Prepass: both inputs, 32 threads/row. Also zeroes `counter`.
  prep_kernel<<<dim3(2 * BATCH * NPTS * 32 / 256), dim3(256), 0, stream>>>(
      X, Y, Xbf, Ybf, x2, y2, counter);

  // Main: (mq=8, ntile=32, b=8) = 2048 blocks.
  chamfer_main<<<dim3(MQ, 32, 8), dim3(256), 0, stream>>>(
      (const unsigned short*)Xbf, (const unsigned short*)Ybf, x2, y2, rowpart, colpart);

  // Final min/sqrt/mean (self-finalizing via ticket).
  reduce_kernel<<<dim3(BATCH * NPTS / 256), dim3(256), 0, stream>>>(
      rowpart, colpart, partials, counter, out);
}

// Round 7
// 147.149 us; speedup vs baseline: 1.0186x; 1.0186x over previous
//
#include <hip/hip_runtime.h>

// Problem constants (fixed by reference setup_inputs)
#define BATCH 8
#define NPTS  4096   // N == M == 4096
#define KD    64
#define MQ    8      // m-strips: each block walks 512 cols = 4 tiles of 128
#define WALK  4
#define FINF  3.0e38f

typedef float f32x4 __attribute__((ext_vector_type(4)));
typedef float f32x2 __attribute__((ext_vector_type(2)));
typedef short s16x8 __attribute__((ext_vector_type(8)));

__device__ __forceinline__ unsigned int f2bf(float f) {
  // round-to-nearest-even fp32 -> bf16 (inputs finite)
  unsigned int u = __float_as_uint(f);
  u += 0x7FFFu + ((u >> 16) & 1u);
  return u >> 16;
}

__device__ __forceinline__ void stage16(const void* g, void* l) {
  // async global->LDS, 16B/lane; LDS dst = wave-uniform base + lane*16
  __builtin_amdgcn_global_load_lds((const __attribute__((address_space(1))) void*)g,
                                   (__attribute__((address_space(3))) void*)l, 16, 0, 0);
}

__device__ __forceinline__ float min3f(float a, float b, float c) {
  return fminf(fminf(a, b), c);   // compiler folds to v_min3_f32
}

// ---------------------------------------------------------------------------
// Prepass: convert X,Y (fp32 [32768][64]) to bf16 packed (uint [32768][32])
// and compute exact fp32 squared norms. 32 threads per row, 2 floats/thread.
// Also zeroes the reduce-phase counter (stream order makes this race-free).
__global__ __launch_bounds__(256)
void prep_kernel(const float* __restrict__ X, const float* __restrict__ Y,
                 unsigned int* __restrict__ Xbf, unsigned int* __restrict__ Ybf,
                 float* __restrict__ x2, float* __restrict__ y2,
                 unsigned int* __restrict__ counter) {
  int gid = blockIdx.x * 256 + threadIdx.x;
  if (gid == 0) *counter = 0;
  int row = gid >> 5;
  int ki  = gid & 31;
  bool isX = row < BATCH * NPTS;
  int r2 = row & (BATCH * NPTS - 1);
  const float* src = isX ? X : Y;
  f32x2 v = *(const f32x2*)(src + (size_t)r2 * KD + ki * 2);
  float s = v[0] * v[0] + v[1] * v[1];
  #pragma unroll
  for (int m = 16; m >= 1; m >>= 1) s += __shfl_xor(s, m, 64);  // stays in 32-lane half
  unsigned int packed = (f2bf(v[1]) << 16) | f2bf(v[0]);
  (isX ? Xbf : Ybf)[r2 * 32 + ki] = packed;
  if (ki == 0) (isX ? x2 : y2)[r2] = s;
}

// ---------------------------------------------------------------------------
// Main: block = (mq, ntile, b). 128 rows x 512 cols (4 m-tiles of 128).
// Waves in 2x2; wave tile 64x64 per m-tile. The WHOLE 64 KB Y strip is staged
// once via global_load_lds (XOR-swizzled), then ONE barrier, then a
// barrier-free 4-tt compute walk (no double-buffer, no per-tt vmcnt drain).
// X fragments direct global->reg (loaded once, 32 regs). yf is read from LDS
// per j-PAIR (16 transient regs) — never 32 live: r6 held yf[4][2] live and
// spilled to scratch (WRITE_SIZE 155 MB ~= the whole 82 us). Budget check:
// xf 32 + x2r 16 + rm 16 + yf 16 + y2c 4 + misc ~20 = ~105 arch + 32 acc,
// far under the (256,2) unified budget of 256. LDS 69 KB -> 2 blocks/CU.
__global__ __launch_bounds__(256, 2)
void chamfer_main(const unsigned short* __restrict__ Xbf,
                  const unsigned short* __restrict__ Ybf,
                  const float* __restrict__ x2g, const float* __restrict__ y2g,
                  float* __restrict__ rowpart,   // [MQ][B*N] min over strip cols (sq)
                  float* __restrict__ colpart) { // [32][B*M] min over ntile rows (sq)
  __shared__ __align__(16) unsigned short Ys[512 * 64];  // 64 KB: whole Y strip
  __shared__ float l_cred[2 * 512];                      // 4 KB: [rowgroup][strip col]
  __shared__ float l_redf[4 * 64];                       // 1 KB: per-wave row-mins

  const int mq = blockIdx.x, ntile = blockIdx.y, b = blockIdx.z;
  const int n0 = ntile * 128;
  const int mbase = mq * 512;
  const int t = threadIdx.x, w = t >> 6, lane = t & 63, c = lane & 15, q = lane >> 4;
  const int wr = (w >> 1) * 64, wc = (w & 1) * 64, rg = w >> 1;

  // staging offset within an 8-row (1KB) group: row=lane>>3, chunk=(lane&7)^(lane>>3)
  const int l8 = lane >> 3;
  const int lane_off = l8 * 128 + (((lane & 7) ^ l8) << 4);

  // Stage the full Y strip: wave w covers rows [w*128, w*128+128) = 16 KB.
  const char* Yg0 = (const char*)(Ybf + (size_t)(b * NPTS + mbase) * KD);
  #pragma unroll
  for (int k = 0; k < 16; ++k) {
    int off8 = (w * 128 + k * 8) * 128;   // byte offset of this 8-row group
    stage16(Yg0 + off8 + lane_off, (char*)Ys + off8);
  }

  // X fragments direct global->reg (A layout: m=c, k=q*8..q*8+7 per ks-half);
  // issued while the LDS DMA is in flight.
  const unsigned short* Xg = Xbf + (size_t)(b * NPTS + n0) * KD;
  s16x8 xf[4][2];
  #pragma unroll
  for (int i = 0; i < 4; ++i) {
    const unsigned short* xr = Xg + (wr + i * 16 + c) * KD + q * 8;
    xf[i][0] = *(const s16x8*)xr;
    xf[i][1] = *(const s16x8*)(xr + 32);
  }

  // x2 fragment (rows wr + i*16 + q*4 + r), fp32, L2-hot. 16 VGPRs.
  const float* x2b = x2g + b * NPTS + n0;
  f32x4 x2r[4];
  #pragma unroll
  for (int i = 0; i < 4; ++i) x2r[i] = *(const f32x4*)(x2b + wr + i * 16 + q * 4);

  float rm[4][4];
  #pragma unroll
  for (int i = 0; i < 4; ++i)
    #pragma unroll
    for (int r = 0; r < 4; ++r) rm[i][r] = FINF;

  const float* y2b = y2g + b * NPTS + mbase;
  const f32x4 zacc = {0.f, 0.f, 0.f, 0.f};
  const int cx = c & 7;

  __syncthreads();  // ONE staging barrier (drains the 16 global_load_lds)

  #pragma unroll
  for (int tt = 0; tt < WALK; ++tt) {
    float y2c[4];
    #pragma unroll
    for (int j = 0; j < 4; ++j) y2c[j] = y2b[tt * 128 + wc + j * 16 + c];

    #pragma unroll
    for (int jp = 0; jp < 2; ++jp) {     // j pair: j0 = 2*jp, j1 = 2*jp+1
      const int j0 = jp * 2, j1 = jp * 2 + 1;
      const unsigned short* yr0 = &Ys[(tt * 128 + wc + j0 * 16 + c) * 64];
      const unsigned short* yr1 = &Ys[(tt * 128 + wc + j1 * 16 + c) * 64];
      s16x8 yf00 = *(const s16x8*)&yr0[(q ^ cx) << 3];
      s16x8 yf01 = *(const s16x8*)&yr0[((4 + q) ^ cx) << 3];
      s16x8 yf10 = *(const s16x8*)&yr1[(q ^ cx) << 3];
      s16x8 yf11 = *(const s16x8*)&yr1[((4 + q) ^ cx) << 3];

      f32x4 acc0[4], acc1[4];
      #pragma unroll
      for (int i = 0; i < 4; ++i) {
        f32x4 a = __builtin_amdgcn_mfma_f32_16x16x32_bf16(xf[i][0], yf00, zacc, 0, 0, 0);
        acc0[i] = __builtin_amdgcn_mfma_f32_16x16x32_bf16(xf[i][1], yf01, a, 0, 0, 0);
        f32x4 bq = __builtin_amdgcn_mfma_f32_16x16x32_bf16(xf[i][0], yf10, zacc, 0, 0, 0);
        acc1[i] = __builtin_amdgcn_mfma_f32_16x16x32_bf16(xf[i][1], yf11, bq, 0, 0, 0);
      }

      // Epilogue with 3-ary mins (v_min3_f32): rm gets both j's in one min3;
      // cm folds r-pairs in one min3.
      float cm0 = FINF, cm1 = FINF;
      #pragma unroll
      for (int i = 0; i < 4; ++i)
        #pragma unroll
        for (int rp = 0; rp < 2; ++rp) {
          const int r0 = rp * 2, r1 = rp * 2 + 1;
          float v00 = acc0[i][r0], v01 = acc0[i][r1];
          float v10 = acc1[i][r0], v11 = acc1[i][r1];
          rm[i][r0] = min3f(rm[i][r0], fmaf(-2.f, v00, y2c[j0]), fmaf(-2.f, v10, y2c[j1]));
          rm[i][r1] = min3f(rm[i][r1], fmaf(-2.f, v01, y2c[j0]), fmaf(-2.f, v11, y2c[j1]));
          cm0 = min3f(cm0, fmaf(-2.f, v00, x2r[i][r0]), fmaf(-2.f, v01, x2r[i][r1]));
          cm1 = min3f(cm1, fmaf(-2.f, v10, x2r[i][r0]), fmaf(-2.f, v11, x2r[i][r1]));
        }
      // col-min over this wave's 64 rows: reduce across the 4 q-groups
      cm0 = fminf(cm0, __shfl_xor(cm0, 16, 64));
      cm0 = fminf(cm0, __shfl_xor(cm0, 32, 64));
      cm1 = fminf(cm1, __shfl_xor(cm1, 16, 64));
      cm1 = fminf(cm1, __shfl_xor(cm1, 32, 64));
      // quad q==j stores col group j (slots wave-private; no barrier needed)
      if (q == j0) l_cred[rg * 512 + tt * 128 + wc + q * 16 + c] = cm0 + y2c[j0];
      else if (q == j1) l_cred[rg * 512 + tt * 128 + wc + q * 16 + c] = cm1 + y2c[j1];
    }
  }

  // Row-min: reduce over the 16 c-lanes within each q-group...
  #pragma unroll
  for (int msk = 1; msk <= 8; msk <<= 1)
    #pragma unroll
    for (int i = 0; i < 4; ++i)
      #pragma unroll
      for (int r = 0; r < 4; ++r)
        rm[i][r] = fminf(rm[i][r], __shfl_xor(rm[i][r], msk, 64));
  // ...then store per-wave row-mins to LDS (literal indices only).
  if (c == 0) {
    #pragma unroll
    for (int i = 0; i < 4; ++i) {
      f32x4 v = {rm[i][0], rm[i][1], rm[i][2], rm[i][3]};
      *(f32x4*)&l_redf[w * 64 + i * 16 + q * 4] = v;
    }
  }
  __syncthreads();  // the only other barrier

  if (t < 128) {
    // combine the 2 col-group waves of each row group, add x2, store
    int g = t >> 6, lr = t & 63;
    float v = fminf(l_redf[(g * 2) * 64 + lr], l_redf[(g * 2 + 1) * 64 + lr]);
    rowpart[mq * (BATCH * NPTS) + b * NPTS + n0 + t] = v + x2b[t];
  } else {
    // combine the 2 row groups for each of the 512 strip cols (y2 already added)
    float* colrow = colpart + (size_t)(ntile * 8 + b) * NPTS + mbase;
    int ct = t - 128;
    #pragma unroll
    for (int u = 0; u < 4; ++u) {
      int cc = ct + u * 128;
      colrow[cc] = fminf(l_cred[cc], l_cred[512 + cc]);
    }
  }
}

// ---------------------------------------------------------------------------
// Final: min over partials, sqrt, mean — self-finalizing (no memset op). The
// last block (device-scope ticket) sums the 128 block partials -> scalar out.
__global__ __launch_bounds__(256)
void reduce_kernel(const float* __restrict__ rowpart, const float* __restrict__ colpart,
                   float* __restrict__ partials, unsigned int* __restrict__ counter,
                   float* __restrict__ out) {
  int i = blockIdx.x * 256 + threadIdx.x;
  const int TOT = BATCH * NPTS;
  float rv = FINF;
  #pragma unroll
  for (int s = 0; s < MQ; ++s) rv = fminf(rv, rowpart[s * TOT + i]);
  float s0 = sqrtf(fmaxf(rv, 0.f));
  float cv = FINF;
  #pragma unroll
  for (int nt = 0; nt < 32; ++nt) cv = fminf(cv, colpart[nt * TOT + i]);
  s0 += sqrtf(fmaxf(cv, 0.f));
  #pragma unroll
  for (int m = 32; m >= 1; m >>= 1) s0 += __shfl_xor(s0, m, 64);
  __shared__ float wsum[4];
  if ((threadIdx.x & 63) == 0) wsum[threadIdx.x >> 6] = s0;
  __syncthreads();

  if (threadIdx.x < 64) {  // wave 0 publishes the block partial, then maybe finalizes
    unsigned int ticket = 0;
    if (threadIdx.x == 0) {
      float bsum = wsum[0] + wsum[1] + wsum[2] + wsum[3];
      atomicExch(&partials[blockIdx.x], bsum);  // device-scope visible store
      __threadfence();
      ticket = atomicAdd(counter, 1);
    }
    ticket = __shfl(ticket, 0, 64);
    if (ticket == 127) {  // all 128 partials published
      float v = atomicAdd(&partials[threadIdx.x], 0.0f) +
                atomicAdd(&partials[threadIdx.x + 64], 0.0f);
      #pragma unroll
      for (int m = 32; m >= 1; m >>= 1) v += __shfl_xor(v, m, 64);
      if (threadIdx.x == 0) out[0] = v * (1.0f / (float)TOT);
    }
  }
}

// ---------------------------------------------------------------------------
extern "C" void kernel_launch(void* const* d_in, const int* in_sizes, int n_in,
                              void* d_out, int out_size, void* d_ws, size_t ws_size,
                              hipStream_t stream) {
  const float* X = (const float*)d_in[0];  // [B, N, 64] fp32
  const float* Y = (const float*)d_in[1];  // [B, M, 64] fp32
  float* out = (float*)d_out;

  // Workspace layout (bytes):
  //   Xbf 4MB | Ybf 4MB | x2 128KB | y2 128KB | rowpart 1MB | colpart 4MB
  //   | partials 512B | counter 4B
  char* ws = (char*)d_ws;
  unsigned int* Xbf = (unsigned int*)ws;                       // packed bf16 pairs
  unsigned int* Ybf = (unsigned int*)(ws + (4u << 20));
  float* x2 = (float*)(ws + (8u << 20));
  float* y2 = (float*)(ws + (8u << 20) + (128u << 10));
  float* rowpart = (float*)(ws + (8u << 20) + (256u << 10));
  float* colpart = (float*)(ws + (9u << 20) + (256u << 10));
  float* partials = (float*)(ws + (13u << 20) + (256u << 10));
  unsigned int* counter = (unsigned int*)(partials + 128);

  // Prepass: both inputs, 32 threads/row. Also zeroes `counter`.
  prep_kernel<<<dim3(2 * BATCH * NPTS * 32 / 256), dim3(256), 0, stream>>>(
      X, Y, Xbf, Ybf, x2, y2, counter);

  // Main: (mq=8, ntile=32, b=8) = 2048 blocks, 2 resident/CU (LDS-capped).
  chamfer_main<<<dim3(MQ, 32, 8), dim3(256), 0, stream>>>(
      (const unsigned short*)Xbf, (const unsigned short*)Ybf, x2, y2, rowpart, colpart);

  // Final min/sqrt/mean (self-finalizing via ticket).
  reduce_kernel<<<dim3(BATCH * NPTS / 256), dim3(256), 0, stream>>>(
      rowpart, colpart, partials, counter, out);
}

// Round 8
// 117.444 us; speedup vs baseline: 1.2763x; 1.2529x over previous
//
#include <hip/hip_runtime.h>

// Problem constants (fixed by reference setup_inputs)
#define BATCH 8
#define NPTS  4096   // N == M == 4096
#define KD    64
#define MQ    16     // m-strips: each block walks 256 cols = 2 tiles of 128
#define WALK  2
#define SCOLS 256
#define FINF  3.0e38f

typedef float f32x4 __attribute__((ext_vector_type(4)));
typedef float f32x2 __attribute__((ext_vector_type(2)));
typedef short s16x8 __attribute__((ext_vector_type(8)));

__device__ __forceinline__ unsigned int f2bf(float f) {
  // round-to-nearest-even fp32 -> bf16 (inputs finite)
  unsigned int u = __float_as_uint(f);
  u += 0x7FFFu + ((u >> 16) & 1u);
  return u >> 16;
}

__device__ __forceinline__ void stage16(const void* g, void* l) {
  // async global->LDS, 16B/lane; LDS dst = wave-uniform base + lane*16
  __builtin_amdgcn_global_load_lds((const __attribute__((address_space(1))) void*)g,
                                   (__attribute__((address_space(3))) void*)l, 16, 0, 0);
}

__device__ __forceinline__ float min3f(float a, float b, float c) {
  return fminf(fminf(a, b), c);   // compiler folds to v_min3_f32
}

// ---------------------------------------------------------------------------
// Prepass: convert X,Y (fp32 [32768][64]) to bf16 packed (uint [32768][32])
// and compute exact fp32 squared norms. 32 threads per row, 2 floats/thread.
// Also zeroes the reduce-phase counter (stream order makes this race-free).
__global__ __launch_bounds__(256)
void prep_kernel(const float* __restrict__ X, const float* __restrict__ Y,
                 unsigned int* __restrict__ Xbf, unsigned int* __restrict__ Ybf,
                 float* __restrict__ x2, float* __restrict__ y2,
                 unsigned int* __restrict__ counter) {
  int gid = blockIdx.x * 256 + threadIdx.x;
  if (gid == 0) *counter = 0;
  int row = gid >> 5;
  int ki  = gid & 31;
  bool isX = row < BATCH * NPTS;
  int r2 = row & (BATCH * NPTS - 1);
  const float* src = isX ? X : Y;
  f32x2 v = *(const f32x2*)(src + (size_t)r2 * KD + ki * 2);
  float s = v[0] * v[0] + v[1] * v[1];
  #pragma unroll
  for (int m = 16; m >= 1; m >>= 1) s += __shfl_xor(s, m, 64);  // stays in 32-lane half
  unsigned int packed = (f2bf(v[1]) << 16) | f2bf(v[0]);
  (isX ? Xbf : Ybf)[r2 * 32 + ki] = packed;
  if (ki == 0) (isX ? x2 : y2)[r2] = s;
}

// ---------------------------------------------------------------------------
// Main: block = (b, mq, ntile) — blockIdx.x = b so linear-id % 8 pins each
// BATCH to one XCD (per-batch working set Xb+Yb = 1 MB fits the 4 MB per-XCD
// L2 -> FETCH collapses). 128 rows x 256 cols per block (2 m-tiles of 128).
// Waves in 2x2; wave tile 64x64 per m-tile. X tile (16 KB) and Y strip
// (32 KB) staged once via global_load_lds (XOR-swizzled); ALL global reads
// (stage + x2 + y2) issue before the ONE barrier; the walk is barrier-free
// and touches only LDS + registers. NO __launch_bounds__ min-waves: the
// (256,2)/(256,3) caps made the allocator split the unified file 128/128 or
// 84/84 and spill ~30 regs/thread -> 96-600 MB phantom WRITE_SIZE in r2-r7.
// Peak arch live here ~100 (xf 32 + rm 16 + x2r 16 + y2 8 + yf 16 + addr).
__global__ __launch_bounds__(256)
void chamfer_main(const unsigned short* __restrict__ Xbf,
                  const unsigned short* __restrict__ Ybf,
                  const float* __restrict__ x2g, const float* __restrict__ y2g,
                  float* __restrict__ rowpart,   // [MQ][B*N] min over strip cols (sq)
                  float* __restrict__ colpart) { // [32][B*M] min over ntile rows (sq)
  __shared__ __align__(16) unsigned short Ys[SCOLS * 64];  // 32 KB: Y strip
  __shared__ __align__(16) unsigned short Xs[128 * 64];    // 16 KB: X tile
  __shared__ float l_cred[2 * SCOLS];                      // 2 KB
  __shared__ float l_redf[4 * 64];                         // 1 KB

  const int b = blockIdx.x, mq = blockIdx.y, ntile = blockIdx.z;
  const int n0 = ntile * 128;
  const int mbase = mq * SCOLS;
  const int t = threadIdx.x, w = t >> 6, lane = t & 63, c = lane & 15, q = lane >> 4;
  const int wr = (w >> 1) * 64, wc = (w & 1) * 64, rg = w >> 1;

  // staging offset within an 8-row (1KB) group: row=lane>>3, chunk=(lane&7)^(lane>>3)
  const int l8 = lane >> 3;
  const int lane_off = l8 * 128 + (((lane & 7) ^ l8) << 4);

  // Stage Y strip (256 rows, wave w covers rows [w*64, w*64+64)) and
  // X tile (128 rows, wave w covers rows [w*32, w*32+32)).
  const char* Yg0 = (const char*)(Ybf + (size_t)(b * NPTS + mbase) * KD);
  const char* Xg0 = (const char*)(Xbf + (size_t)(b * NPTS + n0) * KD);
  #pragma unroll
  for (int k = 0; k < 8; ++k) {
    int off8 = (w * 64 + k * 8) * 128;
    stage16(Yg0 + off8 + lane_off, (char*)Ys + off8);
  }
  #pragma unroll
  for (int k = 0; k < 4; ++k) {
    int off8 = (w * 32 + k * 8) * 128;
    stage16(Xg0 + off8 + lane_off, (char*)Xs + off8);
  }

  // x2 fragment (rows wr + i*16 + q*4 + r) and all strip y2 — issued while
  // the LDS DMA is in flight; no global loads after the barrier.
  const float* x2b = x2g + b * NPTS + n0;
  f32x4 x2r[4];
  #pragma unroll
  for (int i = 0; i < 4; ++i) x2r[i] = *(const f32x4*)(x2b + wr + i * 16 + q * 4);
  const float* y2b = y2g + b * NPTS + mbase;
  float y2all[WALK][4];
  #pragma unroll
  for (int tt = 0; tt < WALK; ++tt)
    #pragma unroll
    for (int j = 0; j < 4; ++j) y2all[tt][j] = y2b[tt * 128 + wc + j * 16 + c];

  float rm[4][4];
  #pragma unroll
  for (int i = 0; i < 4; ++i)
    #pragma unroll
    for (int r = 0; r < 4; ++r) rm[i][r] = FINF;

  const f32x4 zacc = {0.f, 0.f, 0.f, 0.f};
  const int cx = c & 7;

  __syncthreads();  // ONE staging barrier (drains all global_load_lds)

  // X fragments from LDS (swizzled ds_read_b128, conflict-free). 32 VGPRs,
  // held across the whole walk.
  s16x8 xf[4][2];
  #pragma unroll
  for (int i = 0; i < 4; ++i)
    #pragma unroll
    for (int ks = 0; ks < 2; ++ks)
      xf[i][ks] = *(const s16x8*)&Xs[(wr + i * 16 + c) * 64 + ((((ks << 2) + q) ^ cx) << 3)];

  #pragma unroll
  for (int tt = 0; tt < WALK; ++tt) {
    #pragma unroll
    for (int jp = 0; jp < 2; ++jp) {     // j pair: j0 = 2*jp, j1 = 2*jp+1
      const int j0 = jp * 2, j1 = jp * 2 + 1;
      const unsigned short* yr0 = &Ys[(tt * 128 + wc + j0 * 16 + c) * 64];
      const unsigned short* yr1 = &Ys[(tt * 128 + wc + j1 * 16 + c) * 64];
      s16x8 yf00 = *(const s16x8*)&yr0[(q ^ cx) << 3];
      s16x8 yf01 = *(const s16x8*)&yr0[((4 + q) ^ cx) << 3];
      s16x8 yf10 = *(const s16x8*)&yr1[(q ^ cx) << 3];
      s16x8 yf11 = *(const s16x8*)&yr1[((4 + q) ^ cx) << 3];

      f32x4 acc0[4], acc1[4];
      #pragma unroll
      for (int i = 0; i < 4; ++i) {
        f32x4 a = __builtin_amdgcn_mfma_f32_16x16x32_bf16(xf[i][0], yf00, zacc, 0, 0, 0);
        acc0[i] = __builtin_amdgcn_mfma_f32_16x16x32_bf16(xf[i][1], yf01, a, 0, 0, 0);
        f32x4 bq = __builtin_amdgcn_mfma_f32_16x16x32_bf16(xf[i][0], yf10, zacc, 0, 0, 0);
        acc1[i] = __builtin_amdgcn_mfma_f32_16x16x32_bf16(xf[i][1], yf11, bq, 0, 0, 0);
      }

      // Epilogue with 3-ary mins (v_min3_f32).
      float cm0 = FINF, cm1 = FINF;
      #pragma unroll
      for (int i = 0; i < 4; ++i)
        #pragma unroll
        for (int rp = 0; rp < 2; ++rp) {
          const int r0 = rp * 2, r1 = rp * 2 + 1;
          float v00 = acc0[i][r0], v01 = acc0[i][r1];
          float v10 = acc1[i][r0], v11 = acc1[i][r1];
          rm[i][r0] = min3f(rm[i][r0], fmaf(-2.f, v00, y2all[tt][j0]),
                                       fmaf(-2.f, v10, y2all[tt][j1]));
          rm[i][r1] = min3f(rm[i][r1], fmaf(-2.f, v01, y2all[tt][j0]),
                                       fmaf(-2.f, v11, y2all[tt][j1]));
          cm0 = min3f(cm0, fmaf(-2.f, v00, x2r[i][r0]), fmaf(-2.f, v01, x2r[i][r1]));
          cm1 = min3f(cm1, fmaf(-2.f, v10, x2r[i][r0]), fmaf(-2.f, v11, x2r[i][r1]));
        }
      // col-min over this wave's 64 rows: reduce across the 4 q-groups
      cm0 = fminf(cm0, __shfl_xor(cm0, 16, 64));
      cm0 = fminf(cm0, __shfl_xor(cm0, 32, 64));
      cm1 = fminf(cm1, __shfl_xor(cm1, 16, 64));
      cm1 = fminf(cm1, __shfl_xor(cm1, 32, 64));
      // quad q==j stores col group j (slots wave-private; no barrier needed)
      if (q == j0) l_cred[rg * SCOLS + tt * 128 + wc + q * 16 + c] = cm0 + y2all[tt][j0];
      else if (q == j1) l_cred[rg * SCOLS + tt * 128 + wc + q * 16 + c] = cm1 + y2all[tt][j1];
    }
  }

  // Row-min: reduce over the 16 c-lanes within each q-group...
  #pragma unroll
  for (int msk = 1; msk <= 8; msk <<= 1)
    #pragma unroll
    for (int i = 0; i < 4; ++i)
      #pragma unroll
      for (int r = 0; r < 4; ++r)
        rm[i][r] = fminf(rm[i][r], __shfl_xor(rm[i][r], msk, 64));
  // ...then store per-wave row-mins to LDS (literal indices only).
  if (c == 0) {
    #pragma unroll
    for (int i = 0; i < 4; ++i) {
      f32x4 v = {rm[i][0], rm[i][1], rm[i][2], rm[i][3]};
      *(f32x4*)&l_redf[w * 64 + i * 16 + q * 4] = v;
    }
  }
  __syncthreads();  // the only other barrier

  if (t < 128) {
    // combine the 2 col-group waves of each row group, add x2, store
    int g = t >> 6, lr = t & 63;
    float v = fminf(l_redf[(g * 2) * 64 + lr], l_redf[(g * 2 + 1) * 64 + lr]);
    rowpart[mq * (BATCH * NPTS) + b * NPTS + n0 + t] = v + x2b[t];
  } else {
    // combine the 2 row groups for each of the 256 strip cols (y2 already added)
    float* colrow = colpart + (size_t)(ntile * 8 + b) * NPTS + mbase;
    int ct = t - 128;
    #pragma unroll
    for (int u = 0; u < 2; ++u) {
      int cc = ct + u * 128;
      colrow[cc] = fminf(l_cred[cc], l_cred[SCOLS + cc]);
    }
  }
}

// ---------------------------------------------------------------------------
// Final: min over partials, sqrt, mean — self-finalizing (no memset op). The
// last block (device-scope ticket) sums the 128 block partials -> scalar out.
__global__ __launch_bounds__(256)
void reduce_kernel(const float* __restrict__ rowpart, const float* __restrict__ colpart,
                   float* __restrict__ partials, unsigned int* __restrict__ counter,
                   float* __restrict__ out) {
  int i = blockIdx.x * 256 + threadIdx.x;
  const int TOT = BATCH * NPTS;
  float rv = FINF;
  #pragma unroll
  for (int s = 0; s < MQ; ++s) rv = fminf(rv, rowpart[s * TOT + i]);
  float s0 = sqrtf(fmaxf(rv, 0.f));
  float cv = FINF;
  #pragma unroll
  for (int nt = 0; nt < 32; ++nt) cv = fminf(cv, colpart[nt * TOT + i]);
  s0 += sqrtf(fmaxf(cv, 0.f));
  #pragma unroll
  for (int m = 32; m >= 1; m >>= 1) s0 += __shfl_xor(s0, m, 64);
  __shared__ float wsum[4];
  if ((threadIdx.x & 63) == 0) wsum[threadIdx.x >> 6] = s0;
  __syncthreads();

  if (threadIdx.x < 64) {  // wave 0 publishes the block partial, then maybe finalizes
    unsigned int ticket = 0;
    if (threadIdx.x == 0) {
      float bsum = wsum[0] + wsum[1] + wsum[2] + wsum[3];
      atomicExch(&partials[blockIdx.x], bsum);  // device-scope visible store
      __threadfence();
      ticket = atomicAdd(counter, 1);
    }
    ticket = __shfl(ticket, 0, 64);
    if (ticket == 127) {  // all 128 partials published
      float v = atomicAdd(&partials[threadIdx.x], 0.0f) +
                atomicAdd(&partials[threadIdx.x + 64], 0.0f);
      #pragma unroll
      for (int m = 32; m >= 1; m >>= 1) v += __shfl_xor(v, m, 64);
      if (threadIdx.x == 0) out[0] = v * (1.0f / (float)TOT);
    }
  }
}

// ---------------------------------------------------------------------------
extern "C" void kernel_launch(void* const* d_in, const int* in_sizes, int n_in,
                              void* d_out, int out_size, void* d_ws, size_t ws_size,
                              hipStream_t stream) {
  const float* X = (const float*)d_in[0];  // [B, N, 64] fp32
  const float* Y = (const float*)d_in[1];  // [B, M, 64] fp32
  float* out = (float*)d_out;

  // Workspace layout (bytes):
  //   Xbf 4MB @0 | Ybf 4MB @4MB | x2 128KB @8MB | y2 128KB @8.125MB
  //   | rowpart 2MB @8.25MB | colpart 4MB @10.25MB | partials+counter @14.25MB
  char* ws = (char*)d_ws;
  unsigned int* Xbf = (unsigned int*)ws;                       // packed bf16 pairs
  unsigned int* Ybf = (unsigned int*)(ws + (4u << 20));
  float* x2 = (float*)(ws + (8u << 20));
  float* y2 = (float*)(ws + (8u << 20) + (128u << 10));
  float* rowpart = (float*)(ws + (8u << 20) + (256u << 10));
  float* colpart = (float*)(ws + (10u << 20) + (256u << 10));
  float* partials = (float*)(ws + (14u << 20) + (256u << 10));
  unsigned int* counter = (unsigned int*)(partials + 128);

  // Prepass: both inputs, 32 threads/row. Also zeroes `counter`.
  prep_kernel<<<dim3(2 * BATCH * NPTS * 32 / 256), dim3(256), 0, stream>>>(
      X, Y, Xbf, Ybf, x2, y2, counter);

  // Main: (b=8, mq=16, ntile=32) = 4096 blocks; blockIdx.x=b pins batch->XCD.
  chamfer_main<<<dim3(BATCH, MQ, 32), dim3(256), 0, stream>>>(
      (const unsigned short*)Xbf, (const unsigned short*)Ybf, x2, y2, rowpart, colpart);

  // Final min/sqrt/mean (self-finalizing via ticket).
  reduce_kernel<<<dim3(BATCH * NPTS / 256), dim3(256), 0, stream>>>(
      rowpart, colpart, partials, counter, out);
}

// Round 9
// 117.300 us; speedup vs baseline: 1.2778x; 1.0012x over previous
//
#include <hip/hip_runtime.h>

// Problem constants (fixed by reference setup_inputs)
#define BATCH 8
#define NPTS  4096   // N == M == 4096
#define KD    64
#define RS    32     // rowpart slices  = m-strips  (4096/128)
#define CS    4      // colpart slices  = n-walks   (4096/1024)
#define NWALK 8      // n-tiles (128 rows) walked per block = 1024 n per block
#define FINF  3.0e38f

typedef float f32x4 __attribute__((ext_vector_type(4)));
typedef float f32x2 __attribute__((ext_vector_type(2)));
typedef short s16x8 __attribute__((ext_vector_type(8)));

__device__ __forceinline__ unsigned int f2bf(float f) {
  // round-to-nearest-even fp32 -> bf16 (inputs finite)
  unsigned int u = __float_as_uint(f);
  u += 0x7FFFu + ((u >> 16) & 1u);
  return u >> 16;
}

__device__ __forceinline__ float min3f(float a, float b, float c) {
  return fminf(fminf(a, b), c);   // compiler folds to v_min3_f32
}

// ---------------------------------------------------------------------------
// Prepass: convert X,Y (fp32 [32768][64]) to bf16 packed (uint [32768][32])
// and compute exact fp32 squared norms. 32 threads per row, 2 floats/thread.
// Also zeroes the reduce-phase counter (stream order makes this race-free).
__global__ __launch_bounds__(256)
void prep_kernel(const float* __restrict__ X, const float* __restrict__ Y,
                 unsigned int* __restrict__ Xbf, unsigned int* __restrict__ Ybf,
                 float* __restrict__ x2, float* __restrict__ y2,
                 unsigned int* __restrict__ counter) {
  int gid = blockIdx.x * 256 + threadIdx.x;
  if (gid == 0) *counter = 0;
  int row = gid >> 5;
  int ki  = gid & 31;
  bool isX = row < BATCH * NPTS;
  int r2 = row & (BATCH * NPTS - 1);
  const float* src = isX ? X : Y;
  f32x2 v = *(const f32x2*)(src + (size_t)r2 * KD + ki * 2);
  float s = v[0] * v[0] + v[1] * v[1];
  #pragma unroll
  for (int m = 16; m >= 1; m >>= 1) s += __shfl_xor(s, m, 64);  // stays in 32-lane half
  unsigned int packed = (f2bf(v[1]) << 16) | f2bf(v[0]);
  (isX ? Xbf : Ybf)[r2 * 32 + ki] = packed;
  if (ki == 0) (isX ? x2 : y2)[r2] = s;
}

// ---------------------------------------------------------------------------
// Main, round-9 restructure. Orientation SWAPPED vs r8: A-operand = Y (m),
// B-operand = X (n)  =>  acc rows (q*4+r) = m, cols (c) = n. Consequences:
//  * colmin[m] (the expensive 16-lane cross-c reduction) is accumulated in
//    registers across the WHOLE 8-tile n-walk and flushed ONCE per block.
//  * rowmin[n] per tile needs only 2 cross-q shuffles per j.
// No LDS staging at all: fragments load direct from L2 (blockIdx.x = b pins
// batch->XCD; r8 measured FETCH 4.3 MB, i.e. fully L2-resident). ZERO
// barriers until the final combine. LDS = 9 KB of reduction slots ->
// occupancy is VGPR-bound (~4 waves/SIMD). k-loop unrolling DISABLED so the
// compiler cannot hoist 8 tiles' xf loads into registers (spill trap of
// r2/r3/r4/r6/r7 — watch WRITE_SIZE ~6 MB / VGPR ~110-160 to confirm).
__global__ __launch_bounds__(256)
void chamfer_main(const unsigned short* __restrict__ Xbf,
                  const unsigned short* __restrict__ Ybf,
                  const float* __restrict__ x2g, const float* __restrict__ y2g,
                  float* __restrict__ rowpart,   // [RS][B*N] min over strip's m (sq)
                  float* __restrict__ colpart) { // [CS][B*M] min over walk's n (sq)
  __shared__ float l_nm[2 * 128 * NWALK];  // 8 KB: [gm][n within walk] rowmin
  __shared__ float l_cm[2 * 128];          // 1 KB: [gn][m within strip] colmin

  const int b = blockIdx.x, ms = blockIdx.y, nw = blockIdx.z;
  const int m0 = ms * 128;           // Y strip base (128 m rows)
  const int n0 = nw * (128 * NWALK); // X walk base (1024 n rows)
  const int t = threadIdx.x, w = t >> 6, lane = t & 63, c = lane & 15, q = lane >> 4;
  const int gm = w >> 1, gn = w & 1;
  const int wm = gm * 64, wn = gn * 64;

  const unsigned short* Yg = Ybf + (size_t)(b * NPTS + m0) * KD;
  const unsigned short* Xg = Xbf + (size_t)(b * NPTS + n0) * KD;

  // A-fragments (Y rows m = wm + i*16 + c), loaded ONCE. 32 VGPRs.
  s16x8 yf[4][2];
  #pragma unroll
  for (int i = 0; i < 4; ++i) {
    const unsigned short* yr = Yg + (wm + i * 16 + c) * KD + q * 8;
    yf[i][0] = *(const s16x8*)yr;
    yf[i][1] = *(const s16x8*)(yr + 32);
  }
  // y2 for this wave's m rows (m = wm + i*16 + q*4 + r). 16 VGPRs.
  const float* y2b = y2g + b * NPTS + m0;
  f32x4 y2r[4];
  #pragma unroll
  for (int i = 0; i < 4; ++i) y2r[i] = *(const f32x4*)(y2b + wm + i * 16 + q * 4);

  float macc[4][4];   // colmin accumulator: min over ALL walked n, per (i,r)
  #pragma unroll
  for (int i = 0; i < 4; ++i)
    #pragma unroll
    for (int r = 0; r < 4; ++r) macc[i][r] = FINF;

  const float* x2b = x2g + b * NPTS + n0;
  const f32x4 zacc = {0.f, 0.f, 0.f, 0.f};

  #pragma clang loop unroll(disable)
  for (int k = 0; k < NWALK; ++k) {
    // B-fragments (X rows n = k*128 + wn + j*16 + c) + x2, direct from L2.
    s16x8 xf[4][2];
    float x2c[4];
    #pragma unroll
    for (int j = 0; j < 4; ++j) {
      const unsigned short* xr = Xg + (k * 128 + wn + j * 16 + c) * KD + q * 8;
      xf[j][0] = *(const s16x8*)xr;
      xf[j][1] = *(const s16x8*)(xr + 32);
      x2c[j] = x2b[k * 128 + wn + j * 16 + c];
    }

    float nm[4] = {FINF, FINF, FINF, FINF};  // rowmin[n] partial, per j
    #pragma unroll
    for (int jp = 0; jp < 2; ++jp) {
      const int j0 = jp * 2, j1 = jp * 2 + 1;
      f32x4 acc0[4], acc1[4];
      #pragma unroll
      for (int i = 0; i < 4; ++i) {
        f32x4 a = __builtin_amdgcn_mfma_f32_16x16x32_bf16(yf[i][0], xf[j0][0], zacc, 0, 0, 0);
        acc0[i] = __builtin_amdgcn_mfma_f32_16x16x32_bf16(yf[i][1], xf[j0][1], a, 0, 0, 0);
        f32x4 bq = __builtin_amdgcn_mfma_f32_16x16x32_bf16(yf[i][0], xf[j1][0], zacc, 0, 0, 0);
        acc1[i] = __builtin_amdgcn_mfma_f32_16x16x32_bf16(yf[i][1], xf[j1][1], bq, 0, 0, 0);
      }
      // Epilogue (v_min3_f32): macc gets both j's in one min3; nm folds r-pairs.
      #pragma unroll
      for (int i = 0; i < 4; ++i)
        #pragma unroll
        for (int rp = 0; rp < 2; ++rp) {
          const int r0 = rp * 2, r1 = rp * 2 + 1;
          float v00 = acc0[i][r0], v01 = acc0[i][r1];
          float v10 = acc1[i][r0], v11 = acc1[i][r1];
          macc[i][r0] = min3f(macc[i][r0], fmaf(-2.f, v00, x2c[j0]), fmaf(-2.f, v10, x2c[j1]));
          macc[i][r1] = min3f(macc[i][r1], fmaf(-2.f, v01, x2c[j0]), fmaf(-2.f, v11, x2c[j1]));
          nm[j0] = min3f(nm[j0], fmaf(-2.f, v00, y2r[i][r0]), fmaf(-2.f, v01, y2r[i][r1]));
          nm[j1] = min3f(nm[j1], fmaf(-2.f, v10, y2r[i][r0]), fmaf(-2.f, v11, y2r[i][r1]));
        }
    }
    // rowmin: reduce over the 4 q-groups (m direction) — 2 shuffles per j.
    #pragma unroll
    for (int j = 0; j < 4; ++j) {
      nm[j] = fminf(nm[j], __shfl_xor(nm[j], 16, 64));
      nm[j] = fminf(nm[j], __shfl_xor(nm[j], 32, 64));
    }
    // quad q stores col group j==q: 64 consecutive floats/wave, wave-private slot.
    float sel = (q == 0) ? nm[0] : (q == 1) ? nm[1] : (q == 2) ? nm[2] : nm[3];
    l_nm[gm * (128 * NWALK) + k * 128 + wn + q * 16 + c] = sel;
  }

  // colmin flush (ONCE per block): reduce macc over the 16 c-lanes...
  #pragma unroll
  for (int msk = 1; msk <= 8; msk <<= 1)
    #pragma unroll
    for (int i = 0; i < 4; ++i)
      #pragma unroll
      for (int r = 0; r < 4; ++r)
        macc[i][r] = fminf(macc[i][r], __shfl_xor(macc[i][r], msk, 64));
  // ...then c==0 lanes store all 16 (literal indices only — dynamic register
  // array indexing forces scratch lowering).
  if (c == 0) {
    #pragma unroll
    for (int i = 0; i < 4; ++i) {
      f32x4 v = {macc[i][0], macc[i][1], macc[i][2], macc[i][3]};
      *(f32x4*)&l_cm[gn * 128 + wm + i * 16 + q * 4] = v;
    }
  }
  __syncthreads();  // the ONLY barrier in the kernel

  // Final combine: rowpart (1024 n, 4 per thread) and colpart (128 m).
  const size_t TOT = (size_t)BATCH * NPTS;
  float* rp_out = rowpart + (size_t)ms * TOT + b * NPTS + n0;
  #pragma unroll
  for (int u = 0; u < 4; ++u) {
    int nn = t + u * 256;
    float v = fminf(l_nm[nn], l_nm[128 * NWALK + nn]);
    rp_out[nn] = v + x2b[nn];
  }
  if (t < 128) {
    float v = fminf(l_cm[t], l_cm[128 + t]);
    colpart[(size_t)nw * TOT + b * NPTS + m0 + t] = v + y2b[t];
  }
}

// ---------------------------------------------------------------------------
// Final: min over partials, sqrt, mean — self-finalizing (no memset op). The
// last block (device-scope ticket) sums the 128 block partials -> scalar out.
__global__ __launch_bounds__(256)
void reduce_kernel(const float* __restrict__ rowpart, const float* __restrict__ colpart,
                   float* __restrict__ partials, unsigned int* __restrict__ counter,
                   float* __restrict__ out) {
  int i = blockIdx.x * 256 + threadIdx.x;
  const int TOT = BATCH * NPTS;
  float rv = FINF;
  #pragma unroll
  for (int s = 0; s < RS; ++s) rv = fminf(rv, rowpart[(size_t)s * TOT + i]);
  float s0 = sqrtf(fmaxf(rv, 0.f));
  float cv = FINF;
  #pragma unroll
  for (int s = 0; s < CS; ++s) cv = fminf(cv, colpart[(size_t)s * TOT + i]);
  s0 += sqrtf(fmaxf(cv, 0.f));
  #pragma unroll
  for (int m = 32; m >= 1; m >>= 1) s0 += __shfl_xor(s0, m, 64);
  __shared__ float wsum[4];
  if ((threadIdx.x & 63) == 0) wsum[threadIdx.x >> 6] = s0;
  __syncthreads();

  if (threadIdx.x < 64) {  // wave 0 publishes the block partial, then maybe finalizes
    unsigned int ticket = 0;
    if (threadIdx.x == 0) {
      float bsum = wsum[0] + wsum[1] + wsum[2] + wsum[3];
      atomicExch(&partials[blockIdx.x], bsum);  // device-scope visible store
      __threadfence();
      ticket = atomicAdd(counter, 1);
    }
    ticket = __shfl(ticket, 0, 64);
    if (ticket == 127) {  // all 128 partials published
      float v = atomicAdd(&partials[threadIdx.x], 0.0f) +
                atomicAdd(&partials[threadIdx.x + 64], 0.0f);
      #pragma unroll
      for (int m = 32; m >= 1; m >>= 1) v += __shfl_xor(v, m, 64);
      if (threadIdx.x == 0) out[0] = v * (1.0f / (float)TOT);
    }
  }
}

// ---------------------------------------------------------------------------
extern "C" void kernel_launch(void* const* d_in, const int* in_sizes, int n_in,
                              void* d_out, int out_size, void* d_ws, size_t ws_size,
                              hipStream_t stream) {
  const float* X = (const float*)d_in[0];  // [B, N, 64] fp32
  const float* Y = (const float*)d_in[1];  // [B, M, 64] fp32
  float* out = (float*)d_out;

  // Workspace layout (bytes):
  //   Xbf 4MB @0 | Ybf 4MB @4MB | x2 128KB @8MB | y2 128KB @8.125MB
  //   | rowpart 4MB @8.25MB | colpart 512KB @12.25MB | partials+counter @13MB
  char* ws = (char*)d_ws;
  unsigned int* Xbf = (unsigned int*)ws;                       // packed bf16 pairs
  unsigned int* Ybf = (unsigned int*)(ws + (4u << 20));
  float* x2 = (float*)(ws + (8u << 20));
  float* y2 = (float*)(ws + (8u << 20) + (128u << 10));
  float* rowpart = (float*)(ws + (8u << 20) + (256u << 10));
  float* colpart = (float*)(ws + (12u << 20) + (256u << 10));
  float* partials = (float*)(ws + (13u << 20));
  unsigned int* counter = (unsigned int*)(partials + 128);

  // Prepass: both inputs, 32 threads/row. Also zeroes `counter`.
  prep_kernel<<<dim3(2 * BATCH * NPTS * 32 / 256), dim3(256), 0, stream>>>(
      X, Y, Xbf, Ybf, x2, y2, counter);

  // Main: (b=8, ms=32, nw=4) = 1024 blocks; blockIdx.x=b pins batch->XCD.
  chamfer_main<<<dim3(BATCH, RS, CS), dim3(256), 0, stream>>>(
      (const unsigned short*)Xbf, (const unsigned short*)Ybf, x2, y2, rowpart, colpart);

  // Final min/sqrt/mean (self-finalizing via ticket).
  reduce_kernel<<<dim3(BATCH * NPTS / 256), dim3(256), 0, stream>>>(
      rowpart, colpart, partials, counter, out);
}